// Round 12
// baseline (795.293 us; speedup 1.0000x reference)
//
#include <hip/hip_runtime.h>
#include <math.h>

// Problem constants
#define NB_ 34
#define NEGV  (-1e9f)
#define SELFV (-5e4f)

typedef __attribute__((ext_vector_type(8))) short short8;
typedef __attribute__((ext_vector_type(4))) float floatx4;

// ---------------- helpers ----------------
__device__ __forceinline__ unsigned short f2bf(float f) {
  unsigned int u = __float_as_uint(f);
  u += 0x7fffu + ((u >> 16) & 1u);           // round-to-nearest-even
  return (unsigned short)(u >> 16);
}
__device__ __forceinline__ float bflo(unsigned int u) { return __uint_as_float(u << 16); }
__device__ __forceinline__ float bfhi(unsigned int u) { return __uint_as_float(u & 0xffff0000u); }

// ---------------- kernels ----------------

// pe[s*512+c] = (c odd ? cos : sin)(s / 10000^(c/256))   — computed once
__global__ void pe_kernel(float* __restrict__ pe) {
  int idx = blockIdx.x*256 + threadIdx.x;            // 262144
  int s = idx >> 9, c = idx & 511;
  float div = powf(10000.0f, (float)c * (1.0f/256.0f));
  float arg = (float)s / div;
  pe[idx] = (c & 1) ? cosf(arg) : sinf(arg);
}

// x[b,t,d] = features[b, t/4, (t%4)*128+d] + pe; dup to x1,x2
__global__ void pos_kernel(const float* __restrict__ feat, const float* __restrict__ pe,
                           float* __restrict__ x1, float* __restrict__ x2) {
  int idx = blockIdx.x*256 + threadIdx.x;            // 2097152
  int d = idx & 127, t = (idx >> 7) & 2047, b = idx >> 18;
  int s = t >> 2, c = ((t & 3) << 7) | d;
  float val = feat[((size_t)b*512 + s)*512 + c] + pe[(s << 9) | c];
  x1[idx] = val; x2[idx] = val;
}

// LayerNorm over 128; optional avg of two inputs; out fp32 or bf16; row remap.
// Rows [rows, rows+memrows) instead copy raw mem_kv rows (bf16) — fused memfill.
__global__ __launch_bounds__(256) void ln_kernel(
    const float* __restrict__ in, const float* __restrict__ in2,
    const float* __restrict__ g, const float* __restrict__ bta,
    void* __restrict__ out, int rows, int ou, int oa, int obf,
    const float* __restrict__ mem, int memrows) {
  int wid = threadIdx.x >> 6, lane = threadIdx.x & 63;
  int row = blockIdx.x*4 + wid;
  if (row >= rows) {
    int mr = row - rows;
    if (!mem || mr >= memrows) return;
    int bb = mr >> 7, r = mr & 127;
    int orow2 = bb*2176 + 2048 + r;
    float2 mv = ((const float2*)(mem + (size_t)r*128))[lane];
    ((unsigned int*)out)[(size_t)orow2*64 + lane] =
        (unsigned int)f2bf(mv.x) | ((unsigned int)f2bf(mv.y) << 16);
    return;
  }
  float2 x = ((const float2*)(in + (size_t)row*128))[lane];
  if (in2) {
    float2 y = ((const float2*)(in2 + (size_t)row*128))[lane];
    x.x = 0.5f*(x.x + y.x); x.y = 0.5f*(x.y + y.y);
  }
  float s = x.x + x.y;
#pragma unroll
  for (int m = 1; m < 64; m <<= 1) s += __shfl_xor(s, m, 64);
  float mean = s * (1.0f/128.0f);
  float dx = x.x - mean, dy = x.y - mean;
  float v = dx*dx + dy*dy;
#pragma unroll
  for (int m = 1; m < 64; m <<= 1) v += __shfl_xor(v, m, 64);
  float inv = 1.0f / sqrtf(v*(1.0f/128.0f) + 1e-5f);
  int orow = (ou == oa) ? row : (row/ou)*oa + (row%ou);
  float2 gg = ((const float2*)g)[lane];
  float2 bb = ((const float2*)bta)[lane];
  float ox = dx*inv*gg.x + bb.x, oy = dy*inv*gg.y + bb.y;
  if (obf) {
    ((unsigned int*)out)[(size_t)orow*64 + lane] =
        (unsigned int)f2bf(ox) | ((unsigned int)f2bf(oy) << 16);
  } else {
    float2 o; o.x = ox; o.y = oy;
    ((float2*)((float*)out + (size_t)orow*128))[lane] = o;
  }
}

// all 10 weight converts in one launch: W fp32 [K,N] -> Wt bf16 [N,K]
__global__ void wconv_all(const float* __restrict__ w_qk, const float* __restrict__ w_v,
                          const float* __restrict__ w_out, const float* __restrict__ ffw1,
                          const float* __restrict__ ffw2, unsigned short* __restrict__ wt) {
  int idx = blockIdx.x*256 + threadIdx.x;            // 10*65536 = 655360
  int m = idx >> 16, j = idx & 65535;
  int i = m / 5, t = m % 5;
  const float* src; int K;
  switch (t) {
    case 0: src = w_qk; K = 128; break;
    case 1: src = w_v;  K = 128; break;
    case 2: src = w_out;K = 512; break;
    case 3: src = ffw1; K = 128; break;
    default:src = ffw2; K = 512; break;
  }
  src += (size_t)i*65536;
  int N = 65536 / K;
  int k = j % K, n = j / K;
  wt[(size_t)m*65536 + j] = f2bf(src[(size_t)k*N + n]);
}

// bf16 MFMA GEMM: out = act(A_bf16[M,K] @ Wt_bf16[N,K]^T + bias) + resid
__global__ __launch_bounds__(256) void gemm_bf16(
    const unsigned short* __restrict__ A, const unsigned short* __restrict__ Wt,
    const float* __restrict__ bias, const float* __restrict__ resid,
    float* __restrict__ C, unsigned short* __restrict__ Cb,
    int M, int N, int K, int au, int aa, int act) {
  __shared__ __align__(16) unsigned short As[64*40];
  __shared__ __align__(16) unsigned short Bs[64*40];
  int tid = threadIdx.x;
  int wid = tid >> 6, l15 = tid & 15, quad = (tid & 63) >> 4;
  int mb = blockIdx.y, nb = blockIdx.x;
  int r = tid >> 2, cc = (tid & 3)*8;
  int rg = mb*64 + r;
  int rp = (au == aa) ? rg : (rg/au)*aa + (rg%au);
  const unsigned short* arow = A + (size_t)rp*K + cc;
  const unsigned short* brow = Wt + (size_t)(nb*64 + r)*K + cc;
  floatx4 acc[4];
#pragma unroll
  for (int mt = 0; mt < 4; ++mt) acc[mt] = (floatx4){0.f,0.f,0.f,0.f};
  for (int k0 = 0; k0 < K; k0 += 32) {
    *(short8*)&As[r*40 + cc] = *(const short8*)(arow + k0);
    *(short8*)&Bs[r*40 + cc] = *(const short8*)(brow + k0);
    __syncthreads();
    short8 bfr = *(const short8*)&Bs[(wid*16 + l15)*40 + quad*8];
#pragma unroll
    for (int mt = 0; mt < 4; ++mt) {
      short8 afr = *(const short8*)&As[(mt*16 + l15)*40 + quad*8];
      acc[mt] = __builtin_amdgcn_mfma_f32_16x16x32_bf16(afr, bfr, acc[mt], 0, 0, 0);
    }
    __syncthreads();
  }
  int n = nb*64 + wid*16 + l15;
  float bi = bias ? bias[n] : 0.f;
#pragma unroll
  for (int mt = 0; mt < 4; ++mt) {
#pragma unroll
    for (int rr = 0; rr < 4; ++rr) {
      int m = mb*64 + mt*16 + quad*4 + rr;
      float val = acc[mt][rr] + bi;
      if (act) val = 0.5f*val*(1.0f + erff(val*0.70710678118654752f));
      if (resid) val += resid[(size_t)m*N + n];
      if (Cb) Cb[(size_t)m*N + n] = f2bf(val);
      else    C[(size_t)m*N + n] = val;
    }
  }
}

// merged QK+V projection: A[17408,128] @ Wqv[1024,128]^T -> qkb/vbb bf16 [17408,512]
__global__ __launch_bounds__(256) void gemm_qv(
    const unsigned short* __restrict__ A, const unsigned short* __restrict__ Wt,
    unsigned short* __restrict__ Q, unsigned short* __restrict__ V) {
  __shared__ __align__(16) unsigned short As[64*40];
  __shared__ __align__(16) unsigned short Bs[64*40];
  int tid = threadIdx.x;
  int wid = tid >> 6, l15 = tid & 15, quad = (tid & 63) >> 4;
  int mb = blockIdx.y, nb = blockIdx.x;               // (272, 16)
  int r = tid >> 2, cc = (tid & 3)*8;
  const unsigned short* arow = A + (size_t)(mb*64 + r)*128 + cc;
  const unsigned short* brow = Wt + (size_t)(nb*64 + r)*128 + cc;
  floatx4 acc[4];
#pragma unroll
  for (int mt = 0; mt < 4; ++mt) acc[mt] = (floatx4){0.f,0.f,0.f,0.f};
#pragma unroll
  for (int k0 = 0; k0 < 128; k0 += 32) {
    *(short8*)&As[r*40 + cc] = *(const short8*)(arow + k0);
    *(short8*)&Bs[r*40 + cc] = *(const short8*)(brow + k0);
    __syncthreads();
    short8 bfr = *(const short8*)&Bs[(wid*16 + l15)*40 + quad*8];
#pragma unroll
    for (int mt = 0; mt < 4; ++mt) {
      short8 afr = *(const short8*)&As[(mt*16 + l15)*40 + quad*8];
      acc[mt] = __builtin_amdgcn_mfma_f32_16x16x32_bf16(afr, bfr, acc[mt], 0, 0, 0);
    }
    __syncthreads();
  }
  int n = nb*64 + wid*16 + l15;                       // 0..1023
#pragma unroll
  for (int mt = 0; mt < 4; ++mt) {
#pragma unroll
    for (int rr = 0; rr < 4; ++rr) {
      int m = mb*64 + mt*16 + quad*4 + rr;
      unsigned short bv = f2bf(acc[mt][rr]);
      if (n < 512) Q[(size_t)m*512 + n] = bv;
      else         V[(size_t)m*512 + (n - 512)] = bv;
    }
  }
}

// fused per-(row, head) inverse norm + LSH bucket hashing (heads 2..7).
// ss expression order matches r11 norm_kernel exactly (bit-identical nrm).
__global__ __launch_bounds__(256) void normhash_kernel(
    const unsigned short* __restrict__ qkb, const float* __restrict__ rot,
    float* __restrict__ nrm, int* __restrict__ bucket) {
  __shared__ float rl[64*68];
  for (int l = threadIdx.x; l < 4352; l += 256) rl[l] = rot[l];
  __syncthreads();
  int idx = blockIdx.x*256 + threadIdx.x;            // 139264
  int head = idx & 7, row = idx >> 3;                // row = b*2176 + t
  const uint4* src = (const uint4*)(qkb + (size_t)row*512 + head*64);
  float q[64];
  float ss = 0.f;
#pragma unroll
  for (int k = 0; k < 8; ++k) {
    uint4 u = src[k];
    ss += bflo(u.x)*bflo(u.x) + bfhi(u.x)*bfhi(u.x)
        + bflo(u.y)*bflo(u.y) + bfhi(u.y)*bfhi(u.y)
        + bflo(u.z)*bflo(u.z) + bfhi(u.z)*bfhi(u.z)
        + bflo(u.w)*bflo(u.w) + bfhi(u.w)*bfhi(u.w);
    q[8*k+0]=bflo(u.x); q[8*k+1]=bfhi(u.x);
    q[8*k+2]=bflo(u.y); q[8*k+3]=bfhi(u.y);
    q[8*k+4]=bflo(u.z); q[8*k+5]=bfhi(u.z);
    q[8*k+6]=bflo(u.w); q[8*k+7]=bfhi(u.w);
  }
  int b = row / 2176, t = row % 2176;
  nrm[((size_t)b*8 + head)*2176 + t] = 1.0f / fmaxf(sqrtf(ss), 1e-12f);
  if (head < 2) return;
  int bh = b*6 + (head - 2);
  for (int h = 0; h < 4; ++h) {
    float rv[17];
#pragma unroll
    for (int k = 0; k < 17; ++k) rv[k] = 0.f;
    for (int d = 0; d < 64; ++d) {
      float qd = q[d];
      const float* rp = &rl[d*68 + h*17];
#pragma unroll
      for (int k = 0; k < 17; ++k) rv[k] = fmaf(qd, rp[k], rv[k]);
    }
    float best = rv[0]; int bi = 0;
#pragma unroll
    for (int k = 1; k < 34; ++k) {
      float val = (k < 17) ? rv[k] : -rv[k-17];
      if (val > best) { best = val; bi = k; }
    }
    bucket[(size_t)(bh*4 + h)*2176 + t] = bi;
  }
}

// ---- fused attention: blocks [0,3264) = LSH chunk-pair (r7 structure),
//      blocks [3264,3808) = local split-K (r7 structure). LDS 63,488 both paths.
__global__ __launch_bounds__(128) void fused_attn(
    const unsigned short* __restrict__ qkb, const unsigned short* __restrict__ vbb,
    const float* __restrict__ nrm, const int* __restrict__ st,
    unsigned short* __restrict__ o_all, float* __restrict__ logits,
    unsigned short* __restrict__ opart, float* __restrict__ lpart) {
  __shared__ __align__(16) unsigned char shraw[63488];
  int tid = threadIdx.x;

  if (blockIdx.x < 3264) {
    // ======================= LSH path (r7 exact) =======================
    unsigned short* qq = (unsigned short*)shraw;                 // 192*72
    unsigned short* vt = (unsigned short*)(shraw + 27648);       // 64*200
    unsigned short* ptile = (unsigned short*)(shraw + 53248);    // 2*16*136
    int*   tkl  = (int*)(shraw + 61952);                         // 192
    float* invn = (float*)(shraw + 62720);                       // 192

    int blk = blockIdx.x;                 // bh*68 + pair
    int bh = blk / 68, pair = blk % 68;
    int c0 = pair*2;
    int b = bh / 6, coloff = (2 + bh % 6)*64;
    const float* nrmh = nrm + ((size_t)b*8 + 2 + bh % 6)*2176;

#pragma unroll
    for (int rr = 0; rr < 2; ++rr) {
      if (rr == 1 && tid >= 64) break;
      int r = (rr == 0) ? tid : 128 + tid;
      int cr = c0 - 1 + (r >> 6); if (cr < 0) cr += 136;
      int p = st[(size_t)bh*8704 + cr*64 + (r & 63)];
      tkl[r] = p;
      invn[r] = nrmh[p];
      const unsigned short* qr = qkb + ((size_t)(b*2176 + p)*512 + coloff);
#pragma unroll
      for (int k = 0; k < 8; ++k) *(uint4*)&qq[r*72 + k*8] = ((const uint4*)qr)[k];
    }
    if (tid < 96) {
      int r0 = 2*tid, r1 = r0 + 1;
      int cr0 = c0 - 1 + (r0 >> 6); if (cr0 < 0) cr0 += 136;
      int cr1 = c0 - 1 + (r1 >> 6); if (cr1 < 0) cr1 += 136;
      int p0 = st[(size_t)bh*8704 + cr0*64 + (r0 & 63)];
      int p1 = st[(size_t)bh*8704 + cr1*64 + (r1 & 63)];
      const unsigned short* a = vbb + ((size_t)(b*2176 + p0)*512 + coloff);
      const unsigned short* c = vbb + ((size_t)(b*2176 + p1)*512 + coloff);
      unsigned int* vt32 = (unsigned int*)vt;               // pitch 100 uints
#pragma unroll
      for (int k = 0; k < 8; ++k) {
        uint4 ua = ((const uint4*)a)[k];
        uint4 uc = ((const uint4*)c)[k];
        const unsigned short* pa = (const unsigned short*)&ua;
        const unsigned short* pc = (const unsigned short*)&uc;
#pragma unroll
        for (int j = 0; j < 8; ++j) {
          int d = 8*k + j;
          vt32[d*100 + tid] = (unsigned int)pa[j] | ((unsigned int)pc[j] << 16);
        }
      }
    }
    __syncthreads();

    int wid = tid >> 6, l15 = tid & 15, quad = (tid & 63) >> 4;
    int kbase = wid*64, qbase = 64 + wid*64;
    int c = c0 + wid;
    int h = c / NB_;
    float sm8[8]; int tk8[8];
#pragma unroll
    for (int nt = 0; nt < 8; ++nt) {
      int kr = kbase + nt*16 + l15;
      sm8[nt] = invn[kr] * 0.125f;
      tk8[nt] = tkl[kr];
    }
    float* logrow = logits + (size_t)(bh*4 + h)*2176;
    unsigned short* obase = o_all + (size_t)(bh*4 + h)*2176*64;
    unsigned short* pt = ptile + wid*(16*136);

#pragma unroll
    for (int mt = 0; mt < 4; ++mt) {
      floatx4 acc[8];
#pragma unroll
      for (int nt = 0; nt < 8; ++nt) acc[nt] = (floatx4){0.f,0.f,0.f,0.f};
#pragma unroll
      for (int ks = 0; ks < 2; ++ks) {
        short8 afr = *(const short8*)&qq[(qbase + mt*16 + l15)*72 + ks*32 + quad*8];
#pragma unroll
        for (int nt = 0; nt < 8; ++nt) {
          short8 bfr = *(const short8*)&qq[(kbase + nt*16 + l15)*72 + ks*32 + quad*8];
          acc[nt] = __builtin_amdgcn_mfma_f32_16x16x32_bf16(afr, bfr, acc[nt], 0, 0, 0);
        }
      }
      float invl[4];
#pragma unroll
      for (int r = 0; r < 4; ++r) {
        int t_q = tkl[qbase + mt*16 + quad*4 + r];
        float sv8[8]; float mx = -INFINITY;
#pragma unroll
        for (int nt = 0; nt < 8; ++nt) {
          float sc = acc[nt][r] * sm8[nt];
          int t_k = tk8[nt];
          sc = (t_k > t_q) ? NEGV : (t_k == t_q ? SELFV : sc);
          sv8[nt] = sc; mx = fmaxf(mx, sc);
        }
#pragma unroll
        for (int m2 = 1; m2 < 16; m2 <<= 1) mx = fmaxf(mx, __shfl_xor(mx, m2, 64));
        float l = 0.f;
#pragma unroll
        for (int nt = 0; nt < 8; ++nt) { float pe = expf(sv8[nt] - mx); sv8[nt] = pe; l += pe; }
#pragma unroll
        for (int m2 = 1; m2 < 16; m2 <<= 1) l += __shfl_xor(l, m2, 64);
        invl[r] = 1.0f / l;
#pragma unroll
        for (int nt = 0; nt < 8; ++nt)
          pt[(quad*4 + r)*136 + nt*16 + l15] = f2bf(sv8[nt]);
        if (l15 == 0) logrow[t_q] = mx + logf(l);
      }
#pragma unroll
      for (int nt = 0; nt < 4; ++nt) {
        floatx4 po = (floatx4){0.f,0.f,0.f,0.f};
#pragma unroll
        for (int ks = 0; ks < 4; ++ks) {
          short8 afr = *(const short8*)&pt[l15*136 + ks*32 + quad*8];
          short8 bfr = *(const short8*)&vt[(nt*16 + l15)*200 + kbase + ks*32 + quad*8];
          po = __builtin_amdgcn_mfma_f32_16x16x32_bf16(afr, bfr, po, 0, 0, 0);
        }
        int d = nt*16 + l15;
#pragma unroll
        for (int r = 0; r < 4; ++r) {
          int p_q = tkl[qbase + mt*16 + quad*4 + r];
          obase[(size_t)p_q*64 + d] = f2bf(po[r] * invl[r]);
        }
      }
    }
    return;
  }

  // ======================= local path (r7 exact) =======================
  {
    unsigned short* qq = (unsigned short*)shraw;                 // 128*72
    unsigned short* kk = (unsigned short*)(shraw + 18432);       // 128*72
    unsigned short* vt = (unsigned short*)(shraw + 36864);       // 64*136
    unsigned short* ptile = (unsigned short*)(shraw + 54272);    // 2*16*136
    float* invn = (float*)(shraw + 62976);                       // 128

    int blk = blockIdx.x - 3264;
    int part = blk & 1;
    int bw = blk >> 1;
    int bh = bw / 17, w = bw % 17;
    int b = bh >> 1, coloff = (bh & 1)*64;
    int t_qbase = w*128;

    unsigned short* obase = opart + (size_t)(part*16 + bh)*2176*64;
    float* lbase = lpart + (size_t)(part*16 + bh)*2176;

    if (part == 0 && w == 0) {          // fully masked part: O=0, LSE=-1e9
      uint4 z = {0,0,0,0};
      uint4* orow = (uint4*)(obase + (size_t)tid*64);
#pragma unroll
      for (int j = 0; j < 8; ++j) orow[j] = z;
      lbase[tid] = -1e9f;
      return;
    }

    int tkbase = part ? t_qbase : (t_qbase - 128);
    const float* nrmh = nrm + ((size_t)b*8 + (bh & 1))*2176;
    invn[tid] = nrmh[tkbase + tid];

    {
      const unsigned short* qr = qkb + ((size_t)(b*2176 + t_qbase + tid)*512 + coloff);
#pragma unroll
      for (int k = 0; k < 8; ++k) *(uint4*)&qq[tid*72 + k*8] = ((const uint4*)qr)[k];
    }
    if (part == 0) {
      const unsigned short* qr = qkb + ((size_t)(b*2176 + t_qbase - 128 + tid)*512 + coloff);
#pragma unroll
      for (int k = 0; k < 8; ++k) *(uint4*)&kk[tid*72 + k*8] = ((const uint4*)qr)[k];
    }
    if (tid < 64) {
      const unsigned short* vrA = vbb + ((size_t)(b*2176 + tkbase + 2*tid)*512 + coloff);
      const unsigned short* vrB = vrA + 512;
      unsigned int* vt32 = (unsigned int*)vt;          // pitch 68 uints
#pragma unroll
      for (int k = 0; k < 8; ++k) {
        uint4 ua = ((const uint4*)vrA)[k];
        uint4 uc = ((const uint4*)vrB)[k];
        const unsigned short* pa = (const unsigned short*)&ua;
        const unsigned short* pc = (const unsigned short*)&uc;
#pragma unroll
        for (int j = 0; j < 8; ++j) {
          int d = 8*k + j;
          vt32[d*68 + tid] = (unsigned int)pa[j] | ((unsigned int)pc[j] << 16);
        }
      }
    }
    __syncthreads();

    int wid = tid >> 6, l15 = tid & 15, quad = (tid & 63) >> 4;
    const unsigned short* keyrows = part ? qq : kk;
    float sm8[8];
#pragma unroll
    for (int nt = 0; nt < 8; ++nt) sm8[nt] = invn[nt*16 + l15] * 0.125f;
    int qrow0 = wid*64;
    unsigned short* pt = ptile + wid*(16*136);

#pragma unroll
    for (int mt = 0; mt < 4; ++mt) {
      floatx4 acc[8];
#pragma unroll
      for (int nt = 0; nt < 8; ++nt) acc[nt] = (floatx4){0.f,0.f,0.f,0.f};
#pragma unroll
      for (int ks = 0; ks < 2; ++ks) {
        short8 afr = *(const short8*)&qq[(qrow0 + mt*16 + l15)*72 + ks*32 + quad*8];
#pragma unroll
        for (int nt = 0; nt < 8; ++nt) {
          short8 bfr = *(const short8*)&keyrows[(nt*16 + l15)*72 + ks*32 + quad*8];
          acc[nt] = __builtin_amdgcn_mfma_f32_16x16x32_bf16(afr, bfr, acc[nt], 0, 0, 0);
        }
      }
      float invl[4];
#pragma unroll
      for (int r = 0; r < 4; ++r) {
        int row = qrow0 + mt*16 + quad*4 + r;
        int t_q = t_qbase + row;
        float sv[8]; float mx = -INFINITY;
#pragma unroll
        for (int nt = 0; nt < 8; ++nt) {
          float sc = acc[nt][r] * sm8[nt];
          int t_k = tkbase + nt*16 + l15;
          sc = (t_k > t_q) ? NEGV : (t_k == t_q ? SELFV : sc);
          sv[nt] = sc; mx = fmaxf(mx, sc);
        }
#pragma unroll
        for (int m2 = 1; m2 < 16; m2 <<= 1) mx = fmaxf(mx, __shfl_xor(mx, m2, 64));
        float l = 0.f;
#pragma unroll
        for (int nt = 0; nt < 8; ++nt) { float pe = expf(sv[nt] - mx); sv[nt] = pe; l += pe; }
#pragma unroll
        for (int m2 = 1; m2 < 16; m2 <<= 1) l += __shfl_xor(l, m2, 64);
        invl[r] = 1.0f / l;
#pragma unroll
        for (int nt = 0; nt < 8; ++nt)
          pt[(quad*4 + r)*136 + nt*16 + l15] = f2bf(sv[nt]);
        if (l15 == 0) lbase[t_q] = mx + logf(l);
      }
#pragma unroll
      for (int nt = 0; nt < 4; ++nt) {
        floatx4 po = (floatx4){0.f,0.f,0.f,0.f};
#pragma unroll
        for (int ks = 0; ks < 4; ++ks) {
          short8 afr = *(const short8*)&pt[l15*136 + ks*32 + quad*8];
          short8 bfr = *(const short8*)&vt[(nt*16 + l15)*136 + ks*32 + quad*8];
          po = __builtin_amdgcn_mfma_f32_16x16x32_bf16(afr, bfr, po, 0, 0, 0);
        }
        int d = nt*16 + l15;
#pragma unroll
        for (int r = 0; r < 4; ++r) {
          int t_q = t_qbase + qrow0 + mt*16 + quad*4 + r;
          obase[(size_t)t_q*64 + d] = f2bf(po[r] * invl[r]);
        }
      }
    }
  }
}

// stable counting sort per (bh, hash) — per-thread-column histogram + 2-level scan.
__global__ __launch_bounds__(256) void sort_kernel(const int* __restrict__ bucket,
                                                   int* __restrict__ st) {
  __shared__ int sb[2176];
  __shared__ int cnt[NB_*256];
  __shared__ int csum[256];
  int tid = threadIdx.x;
  int bhh = blockIdx.x;
  const int* bin = bucket + (size_t)bhh*2176;
  for (int p = tid; p < 2176; p += 256) sb[p] = bin[p];
#pragma unroll
  for (int j = 0; j < NB_; ++j) cnt[j*256 + tid] = 0;
  __syncthreads();
  int s0 = tid*9;
  int e = s0 + 9; if (e > 2176) e = 2176;
  for (int p = s0; p < e; ++p) cnt[sb[p]*256 + tid] += 1;
  __syncthreads();
  {
    int sum = 0;
    int base0 = tid*NB_;
#pragma unroll
    for (int j = 0; j < NB_; ++j) {
      int v = cnt[base0 + j];
      cnt[base0 + j] = sum;
      sum += v;
    }
    csum[tid] = sum;
  }
  __syncthreads();
  for (int off = 1; off < 256; off <<= 1) {
    int v = (tid >= off) ? csum[tid - off] : 0;
    __syncthreads();
    csum[tid] += v;
    __syncthreads();
  }
  {
    int base = tid ? csum[tid-1] : 0;
    int base0 = tid*NB_;
#pragma unroll
    for (int j = 0; j < NB_; ++j) cnt[base0 + j] += base;
  }
  __syncthreads();
  int bh = bhh >> 2, h = bhh & 3;
  int* outp = st + (size_t)bh*8704 + h*2176;
  for (int p = s0; p < e; ++p) {
    int bk = sb[p];
    int r = cnt[bk*256 + tid]++;
    outp[r] = p;
  }
}

// fused combine: idx<835584 -> 4-hash LSE combine (cols [128,512));
// else local 2-part LSE combine (cols [0,128))
__global__ void comb_fused(const unsigned short* __restrict__ o_all,
                           const float* __restrict__ logits,
                           const unsigned short* __restrict__ opart,
                           const float* __restrict__ lpart,
                           unsigned short* __restrict__ aob) {
  int idx = blockIdx.x*256 + threadIdx.x;            // 1,114,112
  if (idx < 835584) {
    int f8 = idx & 7;
    int p  = (idx >> 3) % 2176;
    int bh = idx / (8*2176);
    float lg0 = logits[(size_t)(bh*4+0)*2176 + p];
    float lg1 = logits[(size_t)(bh*4+1)*2176 + p];
    float lg2 = logits[(size_t)(bh*4+2)*2176 + p];
    float lg3 = logits[(size_t)(bh*4+3)*2176 + p];
    float m = fmaxf(fmaxf(lg0, lg1), fmaxf(lg2, lg3));
    float e0 = expf(lg0-m), e1 = expf(lg1-m), e2 = expf(lg2-m), e3 = expf(lg3-m);
    float inv = 1.0f / (e0+e1+e2+e3);
    float wh[4] = {e0*inv, e1*inv, e2*inv, e3*inv};
    float o[8];
#pragma unroll
    for (int d = 0; d < 8; ++d) o[d] = 0.f;
#pragma unroll
    for (int h = 0; h < 4; ++h) {
      float wg = wh[h];
      uint4 u = ((const uint4*)(o_all + ((size_t)(bh*4+h)*2176 + p)*64))[f8];
      o[0] = fmaf(wg, bflo(u.x), o[0]); o[1] = fmaf(wg, bfhi(u.x), o[1]);
      o[2] = fmaf(wg, bflo(u.y), o[2]); o[3] = fmaf(wg, bfhi(u.y), o[3]);
      o[4] = fmaf(wg, bflo(u.z), o[4]); o[5] = fmaf(wg, bfhi(u.z), o[5]);
      o[6] = fmaf(wg, bflo(u.w), o[6]); o[7] = fmaf(wg, bfhi(u.w), o[7]);
    }
    int b = bh / 6, hh = bh % 6;
    uint4 u;
    u.x = (unsigned int)f2bf(o[0]) | ((unsigned int)f2bf(o[1]) << 16);
    u.y = (unsigned int)f2bf(o[2]) | ((unsigned int)f2bf(o[3]) << 16);
    u.z = (unsigned int)f2bf(o[4]) | ((unsigned int)f2bf(o[5]) << 16);
    u.w = (unsigned int)f2bf(o[6]) | ((unsigned int)f2bf(o[7]) << 16);
    ((uint4*)(aob + ((size_t)(b*2176 + p)*512 + (2+hh)*64 + f8*8)))[0] = u;
  } else {
    int j = idx - 835584;                            // < 278528
    int f8 = j & 7;
    int p  = (j >> 3) % 2176;
    int bh = j / (8*2176);
    float lg0 = lpart[(size_t)bh*2176 + p];
    float lg1 = lpart[(size_t)(16 + bh)*2176 + p];
    float m = fmaxf(lg0, lg1);
    float e0 = expf(lg0 - m), e1 = expf(lg1 - m);
    float inv = 1.0f / (e0 + e1);
    float w0 = e0*inv, w1 = e1*inv;
    uint4 u0 = ((const uint4*)(opart + ((size_t)bh*2176 + p)*64))[f8];
    uint4 u1 = ((const uint4*)(opart + ((size_t)(16 + bh)*2176 + p)*64))[f8];
    uint4 o;
    o.x = (unsigned int)f2bf(w0*bflo(u0.x) + w1*bflo(u1.x)) |
          ((unsigned int)f2bf(w0*bfhi(u0.x) + w1*bfhi(u1.x)) << 16);
    o.y = (unsigned int)f2bf(w0*bflo(u0.y) + w1*bflo(u1.y)) |
          ((unsigned int)f2bf(w0*bfhi(u0.y) + w1*bfhi(u1.y)) << 16);
    o.z = (unsigned int)f2bf(w0*bflo(u0.z) + w1*bflo(u1.z)) |
          ((unsigned int)f2bf(w0*bfhi(u0.z) + w1*bfhi(u1.z)) << 16);
    o.w = (unsigned int)f2bf(w0*bflo(u0.w) + w1*bflo(u1.w)) |
          ((unsigned int)f2bf(w0*bfhi(u0.w) + w1*bfhi(u1.w)) << 16);
    int b = bh >> 1;
    ((uint4*)(aob + ((size_t)(b*2176 + p)*512 + (bh & 1)*64 + f8*8)))[0] = o;
  }
}

// out[b, sub*128+d] = mean_s xln[b, s*4+sub, d] — one wave per output
__global__ __launch_bounds__(256) void pool_kernel(const float* __restrict__ xln,
                                                   float* __restrict__ out) {
  int o = blockIdx.x*4 + (threadIdx.x >> 6);         // 1024 blocks -> 4096 outputs
  int lane = threadIdx.x & 63;
  int c = o & 511, b = o >> 9;
  int sub = c >> 7, d = c & 127;
  const float* p = xln + ((size_t)b*2048 + sub)*128 + d;
  float s = 0.f;
#pragma unroll
  for (int j = 0; j < 8; ++j) s += p[(size_t)(lane + 64*j)*512];
#pragma unroll
  for (int m = 1; m < 64; m <<= 1) s += __shfl_xor(s, m, 64);
  if (lane == 0) out[o] = s * (1.0f/512.0f);
}

// ---------------- host ----------------
// Workspace layout (float slots):
#define OFF_X1    0ull               // 2,097,152
#define OFF_X2    2097152ull         // 2,097,152
#define OFF_XM    4194304ull         // 2,228,224 fp32 (final LN)
#define OFF_XMB   6422528ull         // 1,114,112
#define OFF_QKB   7536640ull         // 8,912,896 slots (qkb bf16 uses first half)
#define OFF_VB    16449536ull        // 8,912,896 (vbb bf16 uses first half)
#define OFF_AOB   25362432ull        // 4,456,448 (aob bf16 / hb bf16, disjoint lifetimes)
#define OFF_OALL  29818880ull        // 13,369,344 (oall bf16 ONLY — no overlays)
#define OFF_LOG   43188224ull        // 417,792
#define OFF_BKT   43606016ull        // 417,792 (int)
#define OFF_ST    44023808ull        // 417,792 (int)
#define OFF_WTB   44441600ull        // 327,680 (10 x 65536 bf16)
#define OFF_NRM   44769280ull        // 139,264 fp32
#define OFF_OPART 44908544ull        // 2,228,224 (32*2176*64 bf16) — disjoint from oall
#define OFF_LPART 47136768ull        // 69,632 fp32
#define OFF_PE    47206400ull        // 262,144 fp32 (positional-encoding table)
#define WS_FLOATS 47468544ull        // ~189.9 MB (round-1 proved >=191.1 MB available)

extern "C" void kernel_launch(void* const* d_in, const int* in_sizes, int n_in,
                              void* d_out, int out_size, void* d_ws, size_t ws_size,
                              hipStream_t stream) {
  (void)in_sizes; (void)n_in; (void)out_size;
  if (ws_size < WS_FLOATS * 4ull) return;

  const float* feat  = (const float*)d_in[0];
  const float* w_qk  = (const float*)d_in[1];
  const float* w_v   = (const float*)d_in[2];
  const float* memkv = (const float*)d_in[3];
  const float* w_out = (const float*)d_in[4];
  const float* b_out = (const float*)d_in[5];
  const float* ln1g  = (const float*)d_in[6];
  const float* ln1b  = (const float*)d_in[7];
  const float* ffw1  = (const float*)d_in[8];
  const float* ffb1  = (const float*)d_in[9];
  const float* ffw2  = (const float*)d_in[10];
  const float* ffb2  = (const float*)d_in[11];
  const float* ln2g  = (const float*)d_in[12];
  const float* ln2b  = (const float*)d_in[13];
  const float* lnfg  = (const float*)d_in[14];
  const float* lnfb  = (const float*)d_in[15];
  const float* rots  = (const float*)d_in[16];

  float* ws = (float*)d_ws;
  float* x1   = ws + OFF_X1;
  float* x2   = ws + OFF_X2;
  float* xm   = ws + OFF_XM;
  unsigned short* xmb = (unsigned short*)(ws + OFF_XMB);
  unsigned short* qkb = (unsigned short*)(ws + OFF_QKB);    // bf16 QK projections
  unsigned short* vbb = (unsigned short*)(ws + OFF_VB);     // bf16 V projections
  unsigned short* aob = (unsigned short*)(ws + OFF_AOB);
  unsigned short* hb  = (unsigned short*)(ws + OFF_AOB);
  unsigned short* oall = (unsigned short*)(ws + OFF_OALL);
  unsigned short* opart = (unsigned short*)(ws + OFF_OPART);  // disjoint from oall
  float* lpart = ws + OFF_LPART;
  float* logi = ws + OFF_LOG;
  int*   bkt  = (int*)(ws + OFF_BKT);
  int*   st   = (int*)(ws + OFF_ST);
  unsigned short* wtb = (unsigned short*)(ws + OFF_WTB);
  float* nrm  = ws + OFF_NRM;
  float* pe   = ws + OFF_PE;
  float* outp = (float*)d_out;

  pe_kernel<<<1024, 256, 0, stream>>>(pe);
  wconv_all<<<2560, 256, 0, stream>>>(w_qk, w_v, w_out, ffw1, ffw2, wtb);
  pos_kernel<<<8192, 256, 0, stream>>>(feat, pe, x1, x2);

  for (int i = 0; i < 2; ++i) {
    const unsigned short* Wqv = wtb + (i*5+0)*65536;        // [1024,128] (Wqk^T || Wv^T)
    const unsigned short* Wo  = wtb + (i*5+2)*65536;
    const unsigned short* W1  = wtb + (i*5+3)*65536;
    const unsigned short* W2  = wtb + (i*5+4)*65536;

    // LN1 + fused mem rows (rows 16384..17407)
    ln_kernel<<<4352, 256, 0, stream>>>(x2, nullptr, ln1g + i*128, ln1b + i*128,
                                        xmb, 16384, 2048, 2176, 1,
                                        memkv + i*16384, 1024);

    // merged QK+V projection, both outputs bf16
    gemm_qv<<<dim3(16, 272), 256, 0, stream>>>(xmb, Wqv, qkb, vbb);

    // fused per-row inverse-norm + LSH hashing
    normhash_kernel<<<544, 256, 0, stream>>>(qkb, rots + i*4352, nrm, bkt);
    sort_kernel<<<192, 256, 0, stream>>>(bkt, st);

    // fused attention: LSH (3264 blocks) + local (544 blocks)
    fused_attn<<<3808, 128, 0, stream>>>(qkb, vbb, nrm, st, oall, logi, opart, lpart);

    // fused combine: lsh cols [128,512) + local cols [0,128)
    comb_fused<<<4352, 256, 0, stream>>>(oall, logi, opart, lpart, aob);

    // y1 = x1 + attn @ w_out + b_out
    gemm_bf16<<<dim3(2, 256), 256, 0, stream>>>(aob, Wo, b_out + i*128, x1, x1, nullptr,
                                                16384, 128, 512, 2048, 2176, 0);
    ln_kernel<<<4096, 256, 0, stream>>>(x1, nullptr, ln2g + i*128, ln2b + i*128,
                                        xmb, 16384, 1, 1, 1, nullptr, 0);
    gemm_bf16<<<dim3(8, 256), 256, 0, stream>>>(xmb, W1, ffb1 + i*512, nullptr, nullptr, hb,
                                                16384, 512, 128, 1, 1, 1);
    gemm_bf16<<<dim3(2, 256), 256, 0, stream>>>(hb, W2, ffb2 + i*128, x2, x2, nullptr,
                                                16384, 128, 512, 1, 1, 0);
  }

  ln_kernel<<<4096, 256, 0, stream>>>(x1, x2, lnfg, lnfb, xm, 16384, 1, 1, 0, nullptr, 0);
  pool_kernel<<<1024, 256, 0, stream>>>(xm, outp);
}

// Round 13
// 698.440 us; speedup vs baseline: 1.1387x; 1.1387x over previous
//
#include <hip/hip_runtime.h>
#include <math.h>

// Problem constants
#define NB_ 34
#define NEGV  (-1e9f)
#define SELFV (-5e4f)

typedef __attribute__((ext_vector_type(8))) short short8;
typedef __attribute__((ext_vector_type(4))) float floatx4;

// ---------------- helpers ----------------
__device__ __forceinline__ unsigned short f2bf(float f) {
  unsigned int u = __float_as_uint(f);
  u += 0x7fffu + ((u >> 16) & 1u);           // round-to-nearest-even
  return (unsigned short)(u >> 16);
}
__device__ __forceinline__ float bflo(unsigned int u) { return __uint_as_float(u << 16); }
__device__ __forceinline__ float bfhi(unsigned int u) { return __uint_as_float(u & 0xffff0000u); }

// unpack 64 bf16 -> fp32
__device__ __forceinline__ void load_row64_bf(const unsigned short* __restrict__ p, float* q) {
#pragma unroll
  for (int k = 0; k < 8; ++k) {
    uint4 u = ((const uint4*)p)[k];
    q[8*k+0]=bflo(u.x); q[8*k+1]=bfhi(u.x);
    q[8*k+2]=bflo(u.y); q[8*k+3]=bfhi(u.y);
    q[8*k+4]=bflo(u.z); q[8*k+5]=bfhi(u.z);
    q[8*k+6]=bflo(u.w); q[8*k+7]=bfhi(u.w);
  }
}

// ---------------- kernels ----------------

// pe[s*512+c] = (c odd ? cos : sin)(s / 10000^(c/256))   — computed once
__global__ void pe_kernel(float* __restrict__ pe) {
  int idx = blockIdx.x*256 + threadIdx.x;            // 262144
  int s = idx >> 9, c = idx & 511;
  float div = powf(10000.0f, (float)c * (1.0f/256.0f));
  float arg = (float)s / div;
  pe[idx] = (c & 1) ? cosf(arg) : sinf(arg);
}

// x[b,t,d] = features[b, t/4, (t%4)*128+d] + pe; dup to x1,x2
__global__ void pos_kernel(const float* __restrict__ feat, const float* __restrict__ pe,
                           float* __restrict__ x1, float* __restrict__ x2) {
  int idx = blockIdx.x*256 + threadIdx.x;            // 2097152
  int d = idx & 127, t = (idx >> 7) & 2047, b = idx >> 18;
  int s = t >> 2, c = ((t & 3) << 7) | d;
  float val = feat[((size_t)b*512 + s)*512 + c] + pe[(s << 9) | c];
  x1[idx] = val; x2[idx] = val;
}

// LayerNorm over 128; optional avg of two inputs; out fp32 or bf16; row remap.
// Rows [rows, rows+memrows) instead copy raw mem_kv rows (bf16) — fused memfill.
__global__ __launch_bounds__(256) void ln_kernel(
    const float* __restrict__ in, const float* __restrict__ in2,
    const float* __restrict__ g, const float* __restrict__ bta,
    void* __restrict__ out, int rows, int ou, int oa, int obf,
    const float* __restrict__ mem, int memrows) {
  int wid = threadIdx.x >> 6, lane = threadIdx.x & 63;
  int row = blockIdx.x*4 + wid;
  if (row >= rows) {
    int mr = row - rows;
    if (!mem || mr >= memrows) return;
    int bb = mr >> 7, r = mr & 127;
    int orow2 = bb*2176 + 2048 + r;
    float2 mv = ((const float2*)(mem + (size_t)r*128))[lane];
    ((unsigned int*)out)[(size_t)orow2*64 + lane] =
        (unsigned int)f2bf(mv.x) | ((unsigned int)f2bf(mv.y) << 16);
    return;
  }
  float2 x = ((const float2*)(in + (size_t)row*128))[lane];
  if (in2) {
    float2 y = ((const float2*)(in2 + (size_t)row*128))[lane];
    x.x = 0.5f*(x.x + y.x); x.y = 0.5f*(x.y + y.y);
  }
  float s = x.x + x.y;
#pragma unroll
  for (int m = 1; m < 64; m <<= 1) s += __shfl_xor(s, m, 64);
  float mean = s * (1.0f/128.0f);
  float dx = x.x - mean, dy = x.y - mean;
  float v = dx*dx + dy*dy;
#pragma unroll
  for (int m = 1; m < 64; m <<= 1) v += __shfl_xor(v, m, 64);
  float inv = 1.0f / sqrtf(v*(1.0f/128.0f) + 1e-5f);
  int orow = (ou == oa) ? row : (row/ou)*oa + (row%ou);
  float2 gg = ((const float2*)g)[lane];
  float2 bb = ((const float2*)bta)[lane];
  float ox = dx*inv*gg.x + bb.x, oy = dy*inv*gg.y + bb.y;
  if (obf) {
    ((unsigned int*)out)[(size_t)orow*64 + lane] =
        (unsigned int)f2bf(ox) | ((unsigned int)f2bf(oy) << 16);
  } else {
    float2 o; o.x = ox; o.y = oy;
    ((float2*)((float*)out + (size_t)orow*128))[lane] = o;
  }
}

// all 10 weight converts in one launch: W fp32 [K,N] -> Wt bf16 [N,K]
__global__ void wconv_all(const float* __restrict__ w_qk, const float* __restrict__ w_v,
                          const float* __restrict__ w_out, const float* __restrict__ ffw1,
                          const float* __restrict__ ffw2, unsigned short* __restrict__ wt) {
  int idx = blockIdx.x*256 + threadIdx.x;            // 10*65536 = 655360
  int m = idx >> 16, j = idx & 65535;
  int i = m / 5, t = m % 5;
  const float* src; int K;
  switch (t) {
    case 0: src = w_qk; K = 128; break;
    case 1: src = w_v;  K = 128; break;
    case 2: src = w_out;K = 512; break;
    case 3: src = ffw1; K = 128; break;
    default:src = ffw2; K = 512; break;
  }
  src += (size_t)i*65536;
  int N = 65536 / K;
  int k = j % K, n = j / K;
  wt[(size_t)m*65536 + j] = f2bf(src[(size_t)k*N + n]);
}

// bf16 MFMA GEMM: out = act(A_bf16[M,K] @ Wt_bf16[N,K]^T + bias) + resid
__global__ __launch_bounds__(256) void gemm_bf16(
    const unsigned short* __restrict__ A, const unsigned short* __restrict__ Wt,
    const float* __restrict__ bias, const float* __restrict__ resid,
    float* __restrict__ C, unsigned short* __restrict__ Cb,
    int M, int N, int K, int au, int aa, int act) {
  __shared__ __align__(16) unsigned short As[64*40];
  __shared__ __align__(16) unsigned short Bs[64*40];
  int tid = threadIdx.x;
  int wid = tid >> 6, l15 = tid & 15, quad = (tid & 63) >> 4;
  int mb = blockIdx.y, nb = blockIdx.x;
  int r = tid >> 2, cc = (tid & 3)*8;
  int rg = mb*64 + r;
  int rp = (au == aa) ? rg : (rg/au)*aa + (rg%au);
  const unsigned short* arow = A + (size_t)rp*K + cc;
  const unsigned short* brow = Wt + (size_t)(nb*64 + r)*K + cc;
  floatx4 acc[4];
#pragma unroll
  for (int mt = 0; mt < 4; ++mt) acc[mt] = (floatx4){0.f,0.f,0.f,0.f};
  for (int k0 = 0; k0 < K; k0 += 32) {
    *(short8*)&As[r*40 + cc] = *(const short8*)(arow + k0);
    *(short8*)&Bs[r*40 + cc] = *(const short8*)(brow + k0);
    __syncthreads();
    short8 bfr = *(const short8*)&Bs[(wid*16 + l15)*40 + quad*8];
#pragma unroll
    for (int mt = 0; mt < 4; ++mt) {
      short8 afr = *(const short8*)&As[(mt*16 + l15)*40 + quad*8];
      acc[mt] = __builtin_amdgcn_mfma_f32_16x16x32_bf16(afr, bfr, acc[mt], 0, 0, 0);
    }
    __syncthreads();
  }
  int n = nb*64 + wid*16 + l15;
  float bi = bias ? bias[n] : 0.f;
#pragma unroll
  for (int mt = 0; mt < 4; ++mt) {
#pragma unroll
    for (int rr = 0; rr < 4; ++rr) {
      int m = mb*64 + mt*16 + quad*4 + rr;
      float val = acc[mt][rr] + bi;
      if (act) val = 0.5f*val*(1.0f + erff(val*0.70710678118654752f));
      if (resid) val += resid[(size_t)m*N + n];
      if (Cb) Cb[(size_t)m*N + n] = f2bf(val);
      else    C[(size_t)m*N + n] = val;
    }
  }
}

// merged QK+V projection: A[17408,128] @ Wqv[1024,128]^T -> qkb/vbb bf16 [17408,512]
__global__ __launch_bounds__(256) void gemm_qv(
    const unsigned short* __restrict__ A, const unsigned short* __restrict__ Wt,
    unsigned short* __restrict__ Q, unsigned short* __restrict__ V) {
  __shared__ __align__(16) unsigned short As[64*40];
  __shared__ __align__(16) unsigned short Bs[64*40];
  int tid = threadIdx.x;
  int wid = tid >> 6, l15 = tid & 15, quad = (tid & 63) >> 4;
  int mb = blockIdx.y, nb = blockIdx.x;               // (272, 16)
  int r = tid >> 2, cc = (tid & 3)*8;
  const unsigned short* arow = A + (size_t)(mb*64 + r)*128 + cc;
  const unsigned short* brow = Wt + (size_t)(nb*64 + r)*128 + cc;
  floatx4 acc[4];
#pragma unroll
  for (int mt = 0; mt < 4; ++mt) acc[mt] = (floatx4){0.f,0.f,0.f,0.f};
#pragma unroll
  for (int k0 = 0; k0 < 128; k0 += 32) {
    *(short8*)&As[r*40 + cc] = *(const short8*)(arow + k0);
    *(short8*)&Bs[r*40 + cc] = *(const short8*)(brow + k0);
    __syncthreads();
    short8 bfr = *(const short8*)&Bs[(wid*16 + l15)*40 + quad*8];
#pragma unroll
    for (int mt = 0; mt < 4; ++mt) {
      short8 afr = *(const short8*)&As[(mt*16 + l15)*40 + quad*8];
      acc[mt] = __builtin_amdgcn_mfma_f32_16x16x32_bf16(afr, bfr, acc[mt], 0, 0, 0);
    }
    __syncthreads();
  }
  int n = nb*64 + wid*16 + l15;                       // 0..1023
#pragma unroll
  for (int mt = 0; mt < 4; ++mt) {
#pragma unroll
    for (int rr = 0; rr < 4; ++rr) {
      int m = mb*64 + mt*16 + quad*4 + rr;
      unsigned short bv = f2bf(acc[mt][rr]);
      if (n < 512) Q[(size_t)m*512 + n] = bv;
      else         V[(size_t)m*512 + (n - 512)] = bv;
    }
  }
}

// per-(b, head, token) inverse norm of 64-dim q (from bf16 qk) — r11 exact
__global__ __launch_bounds__(256) void norm_kernel(const unsigned short* __restrict__ qkb,
                                                   float* __restrict__ nrm) {
  int idx = blockIdx.x*256 + threadIdx.x;            // 139264
  int head = idx & 7, row = idx >> 3;                // row = b*2176 + t
  const uint4* src = (const uint4*)(qkb + (size_t)row*512 + head*64);
  float ss = 0.f;
#pragma unroll
  for (int k = 0; k < 8; ++k) {
    uint4 u = src[k];
    ss += bflo(u.x)*bflo(u.x) + bfhi(u.x)*bfhi(u.x)
        + bflo(u.y)*bflo(u.y) + bfhi(u.y)*bfhi(u.y)
        + bflo(u.z)*bflo(u.z) + bfhi(u.z)*bfhi(u.z)
        + bflo(u.w)*bflo(u.w) + bfhi(u.w)*bfhi(u.w);
  }
  int b = row / 2176, t = row % 2176;
  nrm[((size_t)b*8 + head)*2176 + t] = 1.0f / fmaxf(sqrtf(ss), 1e-12f);
}

// LSH hashing: bucket = argmax over [rv, -rv] (34); fp32 math on bf16 inputs — r11 exact
__global__ __launch_bounds__(256) void hash_kernel(
    const unsigned short* __restrict__ qkb, const float* __restrict__ rot,
    int* __restrict__ bucket) {
  __shared__ float rl[64*68];
  for (int l = threadIdx.x; l < 4352; l += 256) rl[l] = rot[l];
  __syncthreads();
  int idx = blockIdx.x*256 + threadIdx.x;            // 104448
  int p = idx % 2176, bh = idx / 2176;
  int b = bh / 6, hh = bh % 6;
  float q[64];
  load_row64_bf(qkb + ((size_t)(b*2176 + p)*512 + (2+hh)*64), q);
  for (int h = 0; h < 4; ++h) {
    float rv[17];
#pragma unroll
    for (int k = 0; k < 17; ++k) rv[k] = 0.f;
    for (int d = 0; d < 64; ++d) {
      float qd = q[d];
      const float* rp = &rl[d*68 + h*17];
#pragma unroll
      for (int k = 0; k < 17; ++k) rv[k] = fmaf(qd, rp[k], rv[k]);
    }
    float best = rv[0]; int bi = 0;
#pragma unroll
    for (int k = 1; k < 34; ++k) {
      float val = (k < 17) ? rv[k] : -rv[k-17];
      if (val > best) { best = val; bi = k; }
    }
    bucket[(size_t)(bh*4 + h)*2176 + p] = bi;
  }
}

// ---- fused attention: blocks [0,3264) = LSH chunk-pair (r7 structure),
//      blocks [3264,3808) = local split-K (r7 structure). LDS 63,488 both paths.
__global__ __launch_bounds__(128) void fused_attn(
    const unsigned short* __restrict__ qkb, const unsigned short* __restrict__ vbb,
    const float* __restrict__ nrm, const int* __restrict__ st,
    unsigned short* __restrict__ o_all, float* __restrict__ logits,
    unsigned short* __restrict__ opart, float* __restrict__ lpart) {
  __shared__ __align__(16) unsigned char shraw[63488];
  int tid = threadIdx.x;

  if (blockIdx.x < 3264) {
    // ======================= LSH path (r7 exact) =======================
    unsigned short* qq = (unsigned short*)shraw;                 // 192*72
    unsigned short* vt = (unsigned short*)(shraw + 27648);       // 64*200
    unsigned short* ptile = (unsigned short*)(shraw + 53248);    // 2*16*136
    int*   tkl  = (int*)(shraw + 61952);                         // 192
    float* invn = (float*)(shraw + 62720);                       // 192

    int blk = blockIdx.x;                 // bh*68 + pair
    int bh = blk / 68, pair = blk % 68;
    int c0 = pair*2;
    int b = bh / 6, coloff = (2 + bh % 6)*64;
    const float* nrmh = nrm + ((size_t)b*8 + 2 + bh % 6)*2176;

#pragma unroll
    for (int rr = 0; rr < 2; ++rr) {
      if (rr == 1 && tid >= 64) break;
      int r = (rr == 0) ? tid : 128 + tid;
      int cr = c0 - 1 + (r >> 6); if (cr < 0) cr += 136;
      int p = st[(size_t)bh*8704 + cr*64 + (r & 63)];
      tkl[r] = p;
      invn[r] = nrmh[p];
      const unsigned short* qr = qkb + ((size_t)(b*2176 + p)*512 + coloff);
#pragma unroll
      for (int k = 0; k < 8; ++k) *(uint4*)&qq[r*72 + k*8] = ((const uint4*)qr)[k];
    }
    if (tid < 96) {
      int r0 = 2*tid, r1 = r0 + 1;
      int cr0 = c0 - 1 + (r0 >> 6); if (cr0 < 0) cr0 += 136;
      int cr1 = c0 - 1 + (r1 >> 6); if (cr1 < 0) cr1 += 136;
      int p0 = st[(size_t)bh*8704 + cr0*64 + (r0 & 63)];
      int p1 = st[(size_t)bh*8704 + cr1*64 + (r1 & 63)];
      const unsigned short* a = vbb + ((size_t)(b*2176 + p0)*512 + coloff);
      const unsigned short* c = vbb + ((size_t)(b*2176 + p1)*512 + coloff);
      unsigned int* vt32 = (unsigned int*)vt;               // pitch 100 uints
#pragma unroll
      for (int k = 0; k < 8; ++k) {
        uint4 ua = ((const uint4*)a)[k];
        uint4 uc = ((const uint4*)c)[k];
        const unsigned short* pa = (const unsigned short*)&ua;
        const unsigned short* pc = (const unsigned short*)&uc;
#pragma unroll
        for (int j = 0; j < 8; ++j) {
          int d = 8*k + j;
          vt32[d*100 + tid] = (unsigned int)pa[j] | ((unsigned int)pc[j] << 16);
        }
      }
    }
    __syncthreads();

    int wid = tid >> 6, l15 = tid & 15, quad = (tid & 63) >> 4;
    int kbase = wid*64, qbase = 64 + wid*64;
    int c = c0 + wid;
    int h = c / NB_;
    float sm8[8]; int tk8[8];
#pragma unroll
    for (int nt = 0; nt < 8; ++nt) {
      int kr = kbase + nt*16 + l15;
      sm8[nt] = invn[kr] * 0.125f;
      tk8[nt] = tkl[kr];
    }
    float* logrow = logits + (size_t)(bh*4 + h)*2176;
    unsigned short* obase = o_all + (size_t)(bh*4 + h)*2176*64;
    unsigned short* pt = ptile + wid*(16*136);

#pragma unroll
    for (int mt = 0; mt < 4; ++mt) {
      floatx4 acc[8];
#pragma unroll
      for (int nt = 0; nt < 8; ++nt) acc[nt] = (floatx4){0.f,0.f,0.f,0.f};
#pragma unroll
      for (int ks = 0; ks < 2; ++ks) {
        short8 afr = *(const short8*)&qq[(qbase + mt*16 + l15)*72 + ks*32 + quad*8];
#pragma unroll
        for (int nt = 0; nt < 8; ++nt) {
          short8 bfr = *(const short8*)&qq[(kbase + nt*16 + l15)*72 + ks*32 + quad*8];
          acc[nt] = __builtin_amdgcn_mfma_f32_16x16x32_bf16(afr, bfr, acc[nt], 0, 0, 0);
        }
      }
      float invl[4];
#pragma unroll
      for (int r = 0; r < 4; ++r) {
        int t_q = tkl[qbase + mt*16 + quad*4 + r];
        float sv8[8]; float mx = -INFINITY;
#pragma unroll
        for (int nt = 0; nt < 8; ++nt) {
          float sc = acc[nt][r] * sm8[nt];
          int t_k = tk8[nt];
          sc = (t_k > t_q) ? NEGV : (t_k == t_q ? SELFV : sc);
          sv8[nt] = sc; mx = fmaxf(mx, sc);
        }
#pragma unroll
        for (int m2 = 1; m2 < 16; m2 <<= 1) mx = fmaxf(mx, __shfl_xor(mx, m2, 64));
        float l = 0.f;
#pragma unroll
        for (int nt = 0; nt < 8; ++nt) { float pe = expf(sv8[nt] - mx); sv8[nt] = pe; l += pe; }
#pragma unroll
        for (int m2 = 1; m2 < 16; m2 <<= 1) l += __shfl_xor(l, m2, 64);
        invl[r] = 1.0f / l;
#pragma unroll
        for (int nt = 0; nt < 8; ++nt)
          pt[(quad*4 + r)*136 + nt*16 + l15] = f2bf(sv8[nt]);
        if (l15 == 0) logrow[t_q] = mx + logf(l);
      }
#pragma unroll
      for (int nt = 0; nt < 4; ++nt) {
        floatx4 po = (floatx4){0.f,0.f,0.f,0.f};
#pragma unroll
        for (int ks = 0; ks < 4; ++ks) {
          short8 afr = *(const short8*)&pt[l15*136 + ks*32 + quad*8];
          short8 bfr = *(const short8*)&vt[(nt*16 + l15)*200 + kbase + ks*32 + quad*8];
          po = __builtin_amdgcn_mfma_f32_16x16x32_bf16(afr, bfr, po, 0, 0, 0);
        }
        int d = nt*16 + l15;
#pragma unroll
        for (int r = 0; r < 4; ++r) {
          int p_q = tkl[qbase + mt*16 + quad*4 + r];
          obase[(size_t)p_q*64 + d] = f2bf(po[r] * invl[r]);
        }
      }
    }
    return;
  }

  // ======================= local path (r7 exact) =======================
  {
    unsigned short* qq = (unsigned short*)shraw;                 // 128*72
    unsigned short* kk = (unsigned short*)(shraw + 18432);       // 128*72
    unsigned short* vt = (unsigned short*)(shraw + 36864);       // 64*136
    unsigned short* ptile = (unsigned short*)(shraw + 54272);    // 2*16*136
    float* invn = (float*)(shraw + 62976);                       // 128

    int blk = blockIdx.x - 3264;
    int part = blk & 1;
    int bw = blk >> 1;
    int bh = bw / 17, w = bw % 17;
    int b = bh >> 1, coloff = (bh & 1)*64;
    int t_qbase = w*128;

    unsigned short* obase = opart + (size_t)(part*16 + bh)*2176*64;
    float* lbase = lpart + (size_t)(part*16 + bh)*2176;

    if (part == 0 && w == 0) {          // fully masked part: O=0, LSE=-1e9
      uint4 z = {0,0,0,0};
      uint4* orow = (uint4*)(obase + (size_t)tid*64);
#pragma unroll
      for (int j = 0; j < 8; ++j) orow[j] = z;
      lbase[tid] = -1e9f;
      return;
    }

    int tkbase = part ? t_qbase : (t_qbase - 128);
    const float* nrmh = nrm + ((size_t)b*8 + (bh & 1))*2176;
    invn[tid] = nrmh[tkbase + tid];

    {
      const unsigned short* qr = qkb + ((size_t)(b*2176 + t_qbase + tid)*512 + coloff);
#pragma unroll
      for (int k = 0; k < 8; ++k) *(uint4*)&qq[tid*72 + k*8] = ((const uint4*)qr)[k];
    }
    if (part == 0) {
      const unsigned short* qr = qkb + ((size_t)(b*2176 + t_qbase - 128 + tid)*512 + coloff);
#pragma unroll
      for (int k = 0; k < 8; ++k) *(uint4*)&kk[tid*72 + k*8] = ((const uint4*)qr)[k];
    }
    if (tid < 64) {
      const unsigned short* vrA = vbb + ((size_t)(b*2176 + tkbase + 2*tid)*512 + coloff);
      const unsigned short* vrB = vrA + 512;
      unsigned int* vt32 = (unsigned int*)vt;          // pitch 68 uints
#pragma unroll
      for (int k = 0; k < 8; ++k) {
        uint4 ua = ((const uint4*)vrA)[k];
        uint4 uc = ((const uint4*)vrB)[k];
        const unsigned short* pa = (const unsigned short*)&ua;
        const unsigned short* pc = (const unsigned short*)&uc;
#pragma unroll
        for (int j = 0; j < 8; ++j) {
          int d = 8*k + j;
          vt32[d*68 + tid] = (unsigned int)pa[j] | ((unsigned int)pc[j] << 16);
        }
      }
    }
    __syncthreads();

    int wid = tid >> 6, l15 = tid & 15, quad = (tid & 63) >> 4;
    const unsigned short* keyrows = part ? qq : kk;
    float sm8[8];
#pragma unroll
    for (int nt = 0; nt < 8; ++nt) sm8[nt] = invn[nt*16 + l15] * 0.125f;
    int qrow0 = wid*64;
    unsigned short* pt = ptile + wid*(16*136);

#pragma unroll
    for (int mt = 0; mt < 4; ++mt) {
      floatx4 acc[8];
#pragma unroll
      for (int nt = 0; nt < 8; ++nt) acc[nt] = (floatx4){0.f,0.f,0.f,0.f};
#pragma unroll
      for (int ks = 0; ks < 2; ++ks) {
        short8 afr = *(const short8*)&qq[(qrow0 + mt*16 + l15)*72 + ks*32 + quad*8];
#pragma unroll
        for (int nt = 0; nt < 8; ++nt) {
          short8 bfr = *(const short8*)&keyrows[(nt*16 + l15)*72 + ks*32 + quad*8];
          acc[nt] = __builtin_amdgcn_mfma_f32_16x16x32_bf16(afr, bfr, acc[nt], 0, 0, 0);
        }
      }
      float invl[4];
#pragma unroll
      for (int r = 0; r < 4; ++r) {
        int row = qrow0 + mt*16 + quad*4 + r;
        int t_q = t_qbase + row;
        float sv[8]; float mx = -INFINITY;
#pragma unroll
        for (int nt = 0; nt < 8; ++nt) {
          float sc = acc[nt][r] * sm8[nt];
          int t_k = tkbase + nt*16 + l15;
          sc = (t_k > t_q) ? NEGV : (t_k == t_q ? SELFV : sc);
          sv[nt] = sc; mx = fmaxf(mx, sc);
        }
#pragma unroll
        for (int m2 = 1; m2 < 16; m2 <<= 1) mx = fmaxf(mx, __shfl_xor(mx, m2, 64));
        float l = 0.f;
#pragma unroll
        for (int nt = 0; nt < 8; ++nt) { float pe = expf(sv[nt] - mx); sv[nt] = pe; l += pe; }
#pragma unroll
        for (int m2 = 1; m2 < 16; m2 <<= 1) l += __shfl_xor(l, m2, 64);
        invl[r] = 1.0f / l;
#pragma unroll
        for (int nt = 0; nt < 8; ++nt)
          pt[(quad*4 + r)*136 + nt*16 + l15] = f2bf(sv[nt]);
        if (l15 == 0) lbase[t_q] = mx + logf(l);
      }
#pragma unroll
      for (int nt = 0; nt < 4; ++nt) {
        floatx4 po = (floatx4){0.f,0.f,0.f,0.f};
#pragma unroll
        for (int ks = 0; ks < 4; ++ks) {
          short8 afr = *(const short8*)&pt[l15*136 + ks*32 + quad*8];
          short8 bfr = *(const short8*)&vt[(nt*16 + l15)*136 + ks*32 + quad*8];
          po = __builtin_amdgcn_mfma_f32_16x16x32_bf16(afr, bfr, po, 0, 0, 0);
        }
        int d = nt*16 + l15;
#pragma unroll
        for (int r = 0; r < 4; ++r) {
          int t_q = t_qbase + qrow0 + mt*16 + quad*4 + r;
          obase[(size_t)t_q*64 + d] = f2bf(po[r] * invl[r]);
        }
      }
    }
  }
}

// stable counting sort per (bh, hash) — per-thread-column histogram + 2-level scan.
__global__ __launch_bounds__(256) void sort_kernel(const int* __restrict__ bucket,
                                                   int* __restrict__ st) {
  __shared__ int sb[2176];
  __shared__ int cnt[NB_*256];
  __shared__ int csum[256];
  int tid = threadIdx.x;
  int bhh = blockIdx.x;
  const int* bin = bucket + (size_t)bhh*2176;
  for (int p = tid; p < 2176; p += 256) sb[p] = bin[p];
#pragma unroll
  for (int j = 0; j < NB_; ++j) cnt[j*256 + tid] = 0;
  __syncthreads();
  int s0 = tid*9;
  int e = s0 + 9; if (e > 2176) e = 2176;
  for (int p = s0; p < e; ++p) cnt[sb[p]*256 + tid] += 1;
  __syncthreads();
  {
    int sum = 0;
    int base0 = tid*NB_;
#pragma unroll
    for (int j = 0; j < NB_; ++j) {
      int v = cnt[base0 + j];
      cnt[base0 + j] = sum;
      sum += v;
    }
    csum[tid] = sum;
  }
  __syncthreads();
  for (int off = 1; off < 256; off <<= 1) {
    int v = (tid >= off) ? csum[tid - off] : 0;
    __syncthreads();
    csum[tid] += v;
    __syncthreads();
  }
  {
    int base = tid ? csum[tid-1] : 0;
    int base0 = tid*NB_;
#pragma unroll
    for (int j = 0; j < NB_; ++j) cnt[base0 + j] += base;
  }
  __syncthreads();
  int bh = bhh >> 2, h = bhh & 3;
  int* outp = st + (size_t)bh*8704 + h*2176;
  for (int p = s0; p < e; ++p) {
    int bk = sb[p];
    int r = cnt[bk*256 + tid]++;
    outp[r] = p;
  }
}

// fused combine: idx<835584 -> 4-hash LSE combine (cols [128,512));
// else local 2-part LSE combine (cols [0,128))
__global__ void comb_fused(const unsigned short* __restrict__ o_all,
                           const float* __restrict__ logits,
                           const unsigned short* __restrict__ opart,
                           const float* __restrict__ lpart,
                           unsigned short* __restrict__ aob) {
  int idx = blockIdx.x*256 + threadIdx.x;            // 1,114,112
  if (idx < 835584) {
    int f8 = idx & 7;
    int p  = (idx >> 3) % 2176;
    int bh = idx / (8*2176);
    float lg0 = logits[(size_t)(bh*4+0)*2176 + p];
    float lg1 = logits[(size_t)(bh*4+1)*2176 + p];
    float lg2 = logits[(size_t)(bh*4+2)*2176 + p];
    float lg3 = logits[(size_t)(bh*4+3)*2176 + p];
    float m = fmaxf(fmaxf(lg0, lg1), fmaxf(lg2, lg3));
    float e0 = expf(lg0-m), e1 = expf(lg1-m), e2 = expf(lg2-m), e3 = expf(lg3-m);
    float inv = 1.0f / (e0+e1+e2+e3);
    float wh[4] = {e0*inv, e1*inv, e2*inv, e3*inv};
    float o[8];
#pragma unroll
    for (int d = 0; d < 8; ++d) o[d] = 0.f;
#pragma unroll
    for (int h = 0; h < 4; ++h) {
      float wg = wh[h];
      uint4 u = ((const uint4*)(o_all + ((size_t)(bh*4+h)*2176 + p)*64))[f8];
      o[0] = fmaf(wg, bflo(u.x), o[0]); o[1] = fmaf(wg, bfhi(u.x), o[1]);
      o[2] = fmaf(wg, bflo(u.y), o[2]); o[3] = fmaf(wg, bfhi(u.y), o[3]);
      o[4] = fmaf(wg, bflo(u.z), o[4]); o[5] = fmaf(wg, bfhi(u.z), o[5]);
      o[6] = fmaf(wg, bflo(u.w), o[6]); o[7] = fmaf(wg, bfhi(u.w), o[7]);
    }
    int b = bh / 6, hh = bh % 6;
    uint4 u;
    u.x = (unsigned int)f2bf(o[0]) | ((unsigned int)f2bf(o[1]) << 16);
    u.y = (unsigned int)f2bf(o[2]) | ((unsigned int)f2bf(o[3]) << 16);
    u.z = (unsigned int)f2bf(o[4]) | ((unsigned int)f2bf(o[5]) << 16);
    u.w = (unsigned int)f2bf(o[6]) | ((unsigned int)f2bf(o[7]) << 16);
    ((uint4*)(aob + ((size_t)(b*2176 + p)*512 + (2+hh)*64 + f8*8)))[0] = u;
  } else {
    int j = idx - 835584;                            // < 278528
    int f8 = j & 7;
    int p  = (j >> 3) % 2176;
    int bh = j / (8*2176);
    float lg0 = lpart[(size_t)bh*2176 + p];
    float lg1 = lpart[(size_t)(16 + bh)*2176 + p];
    float m = fmaxf(lg0, lg1);
    float e0 = expf(lg0 - m), e1 = expf(lg1 - m);
    float inv = 1.0f / (e0 + e1);
    float w0 = e0*inv, w1 = e1*inv;
    uint4 u0 = ((const uint4*)(opart + ((size_t)bh*2176 + p)*64))[f8];
    uint4 u1 = ((const uint4*)(opart + ((size_t)(16 + bh)*2176 + p)*64))[f8];
    uint4 o;
    o.x = (unsigned int)f2bf(w0*bflo(u0.x) + w1*bflo(u1.x)) |
          ((unsigned int)f2bf(w0*bfhi(u0.x) + w1*bfhi(u1.x)) << 16);
    o.y = (unsigned int)f2bf(w0*bflo(u0.y) + w1*bflo(u1.y)) |
          ((unsigned int)f2bf(w0*bfhi(u0.y) + w1*bfhi(u1.y)) << 16);
    o.z = (unsigned int)f2bf(w0*bflo(u0.z) + w1*bflo(u1.z)) |
          ((unsigned int)f2bf(w0*bfhi(u0.z) + w1*bfhi(u1.z)) << 16);
    o.w = (unsigned int)f2bf(w0*bflo(u0.w) + w1*bflo(u1.w)) |
          ((unsigned int)f2bf(w0*bfhi(u0.w) + w1*bfhi(u1.w)) << 16);
    int b = bh >> 1;
    ((uint4*)(aob + ((size_t)(b*2176 + p)*512 + (bh & 1)*64 + f8*8)))[0] = o;
  }
}

// out[b, sub*128+d] = mean_s xln[b, s*4+sub, d] — one wave per output
__global__ __launch_bounds__(256) void pool_kernel(const float* __restrict__ xln,
                                                   float* __restrict__ out) {
  int o = blockIdx.x*4 + (threadIdx.x >> 6);         // 1024 blocks -> 4096 outputs
  int lane = threadIdx.x & 63;
  int c = o & 511, b = o >> 9;
  int sub = c >> 7, d = c & 127;
  const float* p = xln + ((size_t)b*2048 + sub)*128 + d;
  float s = 0.f;
#pragma unroll
  for (int j = 0; j < 8; ++j) s += p[(size_t)(lane + 64*j)*512];
#pragma unroll
  for (int m = 1; m < 64; m <<= 1) s += __shfl_xor(s, m, 64);
  if (lane == 0) out[o] = s * (1.0f/512.0f);
}

// ---------------- host ----------------
// Workspace layout (float slots):
#define OFF_X1    0ull               // 2,097,152
#define OFF_X2    2097152ull         // 2,097,152
#define OFF_XM    4194304ull         // 2,228,224 fp32 (final LN)
#define OFF_XMB   6422528ull         // 1,114,112
#define OFF_QKB   7536640ull         // 8,912,896 slots (qkb bf16 uses first half)
#define OFF_VB    16449536ull        // 8,912,896 (vbb bf16 uses first half)
#define OFF_AOB   25362432ull        // 4,456,448 (aob bf16 / hb bf16, disjoint lifetimes)
#define OFF_OALL  29818880ull        // 13,369,344 (oall bf16 ONLY — no overlays)
#define OFF_LOG   43188224ull        // 417,792
#define OFF_BKT   43606016ull        // 417,792 (int)
#define OFF_ST    44023808ull        // 417,792 (int)
#define OFF_WTB   44441600ull        // 327,680 (10 x 65536 bf16)
#define OFF_NRM   44769280ull        // 139,264 fp32
#define OFF_OPART 44908544ull        // 2,228,224 (32*2176*64 bf16) — disjoint from oall
#define OFF_LPART 47136768ull        // 69,632 fp32
#define OFF_PE    47206400ull        // 262,144 fp32 (positional-encoding table)
#define WS_FLOATS 47468544ull        // ~189.9 MB (round-1 proved >=191.1 MB available)

extern "C" void kernel_launch(void* const* d_in, const int* in_sizes, int n_in,
                              void* d_out, int out_size, void* d_ws, size_t ws_size,
                              hipStream_t stream) {
  (void)in_sizes; (void)n_in; (void)out_size;
  if (ws_size < WS_FLOATS * 4ull) return;

  const float* feat  = (const float*)d_in[0];
  const float* w_qk  = (const float*)d_in[1];
  const float* w_v   = (const float*)d_in[2];
  const float* memkv = (const float*)d_in[3];
  const float* w_out = (const float*)d_in[4];
  const float* b_out = (const float*)d_in[5];
  const float* ln1g  = (const float*)d_in[6];
  const float* ln1b  = (const float*)d_in[7];
  const float* ffw1  = (const float*)d_in[8];
  const float* ffb1  = (const float*)d_in[9];
  const float* ffw2  = (const float*)d_in[10];
  const float* ffb2  = (const float*)d_in[11];
  const float* ln2g  = (const float*)d_in[12];
  const float* ln2b  = (const float*)d_in[13];
  const float* lnfg  = (const float*)d_in[14];
  const float* lnfb  = (const float*)d_in[15];
  const float* rots  = (const float*)d_in[16];

  float* ws = (float*)d_ws;
  float* x1   = ws + OFF_X1;
  float* x2   = ws + OFF_X2;
  float* xm   = ws + OFF_XM;
  unsigned short* xmb = (unsigned short*)(ws + OFF_XMB);
  unsigned short* qkb = (unsigned short*)(ws + OFF_QKB);    // bf16 QK projections
  unsigned short* vbb = (unsigned short*)(ws + OFF_VB);     // bf16 V projections
  unsigned short* aob = (unsigned short*)(ws + OFF_AOB);
  unsigned short* hb  = (unsigned short*)(ws + OFF_AOB);
  unsigned short* oall = (unsigned short*)(ws + OFF_OALL);
  unsigned short* opart = (unsigned short*)(ws + OFF_OPART);  // disjoint from oall
  float* lpart = ws + OFF_LPART;
  float* logi = ws + OFF_LOG;
  int*   bkt  = (int*)(ws + OFF_BKT);
  int*   st   = (int*)(ws + OFF_ST);
  unsigned short* wtb = (unsigned short*)(ws + OFF_WTB);
  float* nrm  = ws + OFF_NRM;
  float* pe   = ws + OFF_PE;
  float* outp = (float*)d_out;

  pe_kernel<<<1024, 256, 0, stream>>>(pe);
  wconv_all<<<2560, 256, 0, stream>>>(w_qk, w_v, w_out, ffw1, ffw2, wtb);
  pos_kernel<<<8192, 256, 0, stream>>>(feat, pe, x1, x2);

  for (int i = 0; i < 2; ++i) {
    const unsigned short* Wqv = wtb + (i*5+0)*65536;        // [1024,128] (Wqk^T || Wv^T)
    const unsigned short* Wo  = wtb + (i*5+2)*65536;
    const unsigned short* W1  = wtb + (i*5+3)*65536;
    const unsigned short* W2  = wtb + (i*5+4)*65536;

    // LN1 + fused mem rows (rows 16384..17407)
    ln_kernel<<<4352, 256, 0, stream>>>(x2, nullptr, ln1g + i*128, ln1b + i*128,
                                        xmb, 16384, 2048, 2176, 1,
                                        memkv + i*16384, 1024);

    // merged QK+V projection, both outputs bf16
    gemm_qv<<<dim3(16, 272), 256, 0, stream>>>(xmb, Wqv, qkb, vbb);

    // separate norm + hash (r11 proven; r12 fusion regressed)
    norm_kernel<<<544, 256, 0, stream>>>(qkb, nrm);
    hash_kernel<<<408, 256, 0, stream>>>(qkb, rots + i*4352, bkt);
    sort_kernel<<<192, 256, 0, stream>>>(bkt, st);

    // fused attention: LSH (3264 blocks) + local (544 blocks)
    fused_attn<<<3808, 128, 0, stream>>>(qkb, vbb, nrm, st, oall, logi, opart, lpart);

    // fused combine: lsh cols [128,512) + local cols [0,128)
    comb_fused<<<4352, 256, 0, stream>>>(oall, logi, opart, lpart, aob);

    // y1 = x1 + attn @ w_out + b_out
    gemm_bf16<<<dim3(2, 256), 256, 0, stream>>>(aob, Wo, b_out + i*128, x1, x1, nullptr,
                                                16384, 128, 512, 2048, 2176, 0);
    ln_kernel<<<4096, 256, 0, stream>>>(x1, nullptr, ln2g + i*128, ln2b + i*128,
                                        xmb, 16384, 1, 1, 1, nullptr, 0);
    gemm_bf16<<<dim3(8, 256), 256, 0, stream>>>(xmb, W1, ffb1 + i*512, nullptr, nullptr, hb,
                                                16384, 512, 128, 1, 1, 1);
    gemm_bf16<<<dim3(2, 256), 256, 0, stream>>>(hb, W2, ffb2 + i*128, x2, x2, nullptr,
                                                16384, 128, 512, 1, 1, 0);
  }

  ln_kernel<<<4096, 256, 0, stream>>>(x1, x2, lnfg, lnfb, xm, 16384, 1, 1, 0, nullptr, 0);
  pool_kernel<<<1024, 256, 0, stream>>>(xm, outp);
}